// Round 5
// baseline (245.899 us; speedup 1.0000x reference)
//
#include <hip/hip_runtime.h>
#include <cstdint>

// Problem constants (fixed by setup_inputs): B=4, N=16384, P=1024, C=128
#define BQ_B 4
#define BQ_N 16384
#define BQ_P 1024
#define BQ_C 128
#define NS   64
#define R2   0.04f

// Output layout (flat concat, fp32):
//   region 1: new_features (B,131,P,NS)
//   region 2: grouped_xyz  (B,3,P,NS)
//   region 3: idx0         (B,P,NS) stored as float
#define O1 ((size_t)BQ_B * 131 * BQ_P * NS)
#define O2 (O1 + (size_t)BQ_B * 3 * BQ_P * NS)

// ws: features transposed to (B, N, C)
#define WS_T_BYTES ((size_t)BQ_B * BQ_N * BQ_C * 4)

// ---------------- Kernel 1: features (B,C,N) -> ws (B,N,C) ----------------
__global__ __launch_bounds__(256) void transpose_kernel(
    const float* __restrict__ f, float* __restrict__ ft)
{
    const int bid = blockIdx.x;
    const int n0 = (bid & 255) * 64;
    const int c0 = ((bid >> 8) & 1) * 64;
    const int b  = bid >> 9;
    __shared__ float tile[64][65];

    const float* fb = f + ((size_t)b * BQ_C + c0) * BQ_N;
    #pragma unroll
    for (int k = 0; k < 16; ++k) {
        const int cc = k * 4 + (threadIdx.x >> 6);
        const int nn = threadIdx.x & 63;
        tile[cc][nn] = fb[(size_t)cc * BQ_N + n0 + nn];
    }
    __syncthreads();
    float* ob = ft + ((size_t)b * BQ_N + n0) * BQ_C + c0;
    #pragma unroll
    for (int k = 0; k < 16; ++k) {
        const int nn = k * 4 + (threadIdx.x >> 6);
        const int cc = threadIdx.x & 63;
        ob[(size_t)nn * BQ_C + cc] = tile[cc][nn];
    }
}

// ------------- Kernel 2: fused ball query + grouping, 1 block/center -------------
// 256 threads = 4 waves. Round-based cooperative scan (4096 pts/round:
// 4 waves x 16 chunks of 64; masks -> LDS; wave 0 prefix-sums chunk counts;
// all waves scatter ranked indices). Then feature gather via a 32-row
// half-tile (two passes) to keep LDS ~17.8 KB -> 8 blocks/CU, 32 waves/CU.
__global__ __launch_bounds__(256, 8) void query_gather_kernel(
    const float* __restrict__ xyz,      // (B, N, 3)
    const float* __restrict__ new_xyz,  // (B, P, 3)
    const float* __restrict__ ft,       // (B, N, C) transposed
    float* __restrict__ out)
{
#pragma clang fp contract(off)   // match np reference exactly at the radius boundary
    const int center = blockIdx.x;
    const int b = center >> 10;
    const int p = center & (BQ_P - 1);
    const int t = threadIdx.x;
    const int lane = t & 63;
    const int w = t >> 6;               // wave 0..3

    __shared__ unsigned long long smask[64];   // per-chunk hit masks (this round)
    __shared__ int   sprefix[64];              // exclusive rank base per chunk
    __shared__ int   s_total;                  // total hits so far
    __shared__ int   lds_idx[NS];              // first NS ascending hit indices
    __shared__ int   gidx_s[NS];               // gather index per slot (BQ_N = pad)
    __shared__ float tile[32][BQ_C + 1];       // half-tile (pad 129: 2-way banks, free)

    const float cx = new_xyz[center * 3 + 0];
    const float cy = new_xyz[center * 3 + 1];
    const float cz = new_xyz[center * 3 + 2];
    const float* xb = xyz + (size_t)b * BQ_N * 3;

    int total = 0;
    const unsigned long long lmask = (1ull << lane) - 1ull;

    for (int round = 0; round < 4; ++round) {
        const int rbase = round * 4096;
        // ---- masks for my 16 chunks (independent loads, no serial chain) ----
        #pragma unroll
        for (int k = 0; k < 16; ++k) {
            const int j = w * 16 + k;
            const int i = rbase + j * 64 + lane;
            const float dx = xb[i * 3 + 0] - cx;
            const float dy = xb[i * 3 + 1] - cy;
            const float dz = xb[i * 3 + 2] - cz;
            const float d2 = dx * dx + dy * dy + dz * dz;
            const unsigned long long m = __ballot(d2 < R2);
            if (lane == 0) smask[j] = m;
        }
        __syncthreads();   // barrier A: all masks visible

        // ---- wave 0: prefix-sum the 64 chunk counts ----
        if (w == 0) {
            const unsigned long long mm = smask[lane];
            const int cnt = (int)__popcll(mm);
            int x = cnt;
            #pragma unroll
            for (int d = 1; d < 64; d <<= 1) {
                const int y = __shfl_up(x, d, 64);
                if (lane >= d) x += y;
            }
            sprefix[lane] = total + (x - cnt);      // exclusive prefix + base
            if (lane == 63) s_total = total + x;
        }
        __syncthreads();   // barrier B: sprefix/s_total visible

        // ---- scatter ranked indices for my chunks ----
        const int new_total = s_total;
        #pragma unroll
        for (int k = 0; k < 16; ++k) {
            const int j = w * 16 + k;
            const unsigned long long m = smask[j];
            const int baser = sprefix[j];
            if (baser < NS && ((m >> lane) & 1ull)) {
                const int r = baser + (int)__popcll(m & lmask);
                if (r < NS) lds_idx[r] = rbase + j * 64 + lane;
            }
        }
        total = new_total;
        if (new_total >= NS) break;
    }
    __syncthreads();

    // ---- slot assignment + xyz/idx outputs (threads 0..63) ----
    if (t < NS) {
        const int tt = (total > NS) ? NS : total;
        const int first = (total > 0) ? lds_idx[0] : BQ_N;
        const int v = (t < tt) ? lds_idx[t] : BQ_N;
        const int idx0 = (t < tt) ? v : first;
        const int gidx = v;                 // BQ_N for pad slots
        const bool real = gidx < BQ_N;
        gidx_s[t] = gidx;

        out[O2 + (size_t)center * NS + t] = (float)idx0;

        #pragma unroll
        for (int d = 0; d < 3; ++d) {
            const float c = (d == 0) ? cx : ((d == 1) ? cy : cz);
            const float pt = real ? xb[gidx * 3 + d] : 1000000.0f;
            const float g = pt - c;
            out[O1 + ((size_t)(b * 3 + d) * BQ_P + p) * NS + t] = g;
            const float xf = ((g > 100000.0f) ? 0.0f : g) / 0.2f;
            out[((size_t)(b * 131 + d) * BQ_P + p) * NS + t] = xf;
        }
    }
    __syncthreads();

    // ---- feature gather (channels 3..130), two 32-row half-tiles ----
    const float* fb = ft + (size_t)b * BQ_N * BQ_C;
    float* ob = out + ((size_t)(b * 131 + 3) * BQ_P + p) * NS;
    #pragma unroll
    for (int half = 0; half < 2; ++half) {
        // load 32 rows: 2 rows/iter (128 threads x 128 channels contiguous)
        #pragma unroll
        for (int k = 0; k < 16; ++k) {
            const int sl = k * 2 + (t >> 7);
            const int c = t & 127;
            const int gi = gidx_s[half * 32 + sl];
            tile[sl][c] = (gi < BQ_N) ? fb[(size_t)gi * BQ_C + c] : 0.0f;
        }
        __syncthreads();
        // write: 8 channels/iter, 32 threads each (128 B contiguous per channel)
        #pragma unroll
        for (int k = 0; k < 16; ++k) {
            const int c = k * 8 + (t >> 5);
            const int sl = t & 31;
            ob[(size_t)c * (BQ_P * NS) + half * 32 + sl] = tile[sl][c];
        }
        __syncthreads();   // tile reused next half
    }
}

extern "C" void kernel_launch(void* const* d_in, const int* in_sizes, int n_in,
                              void* d_out, int out_size, void* d_ws, size_t ws_size,
                              hipStream_t stream) {
    const float* xyz      = (const float*)d_in[0];  // (4,16384,3)
    const float* new_xyz  = (const float*)d_in[1];  // (4,1024,3)
    const float* features = (const float*)d_in[2];  // (4,128,16384)
    float* out = (float*)d_out;
    float* ft  = (float*)d_ws;

    transpose_kernel<<<dim3(BQ_B * 2 * 256), dim3(256), 0, stream>>>(features, ft);
    query_gather_kernel<<<dim3(BQ_B * BQ_P), dim3(256), 0, stream>>>(xyz, new_xyz, ft, out);
}